// Round 11
// baseline (299.352 us; speedup 1.0000x reference)
//
#include <hip/hip_runtime.h>
#include <math.h>

#define NQ 131072
#define MN 8192
#define NINT 1024          // internal nodes: 8*i+1 < 8192 -> i <= 1023
#define DEPTHT 16
#define EPSD 1e-6f
#define BIGD 1e9f

// ---------------------------------------------------------------------------
// R20. Journal (do not retry):
//  R10 convoy 77.9 | R11 w3->LDS+SMEM mix 80.0 | R12 bank fix neutral
//  R13 half-grid: mlp PER-WAVE LATENCY bound | R14 readlane 114
//  R15 VMEM bcast 224 (h1 spill) | R17 coop fusion 643 (spill; proved ~78us
//  constant harness overhead) | R18 LDS-vec transport 318 (h1 spill)
//  TRANSPORT CONCLUSION: s_load only (keeps weights in the SCALAR file).
//  R20: first STRUCTURAL attack — team-of-2 j-slice. Wall = rows-per-wave x
//  per-row SMEM drain; halve rows-per-wave instead of changing transport.
//  Wave w of a 128-thread block streams w2 rows [50w,50w+50) (s_load loop
//  VERBATIM R0), h2j -> LDS (exact fp32 pass-through); wave 0 then runs the
//  j-ORDERED h3 chain + layer4. Every fmaf has identical operands/order ->
//  bit-identical output (R5 contract).
//  Sentinels: WRITE_SIZE 1088KB (no spill), LDS 25.6KB, mlp 42-55us.
//  If mlp >= 65: structural legs exhausted -> revert R3, declare ROOFLINE.
// ---------------------------------------------------------------------------

// ---------------------------------------------------------------------------
// Kernel 0: transpose W2 [k][j] -> W2T [j][k] (contiguous rows for s_load).
// ---------------------------------------------------------------------------
__global__ __launch_bounds__(256) void transpose_w2(
    const float* __restrict__ W2, float* __restrict__ W2T)
{
    const int i = blockIdx.x * 256 + threadIdx.x;
    if (i < 100 * 100) {
        const int k = i / 100, j = i - k * 100;
        W2T[j * 100 + k] = W2[i];
    }
}

// ---------------------------------------------------------------------------
// Kernel 1: MLP 2 -> 100 -> 100 -> 30 -> 2. Team-of-2 j-slice (R20).
// Block: 128 threads = 2 waves, 64 rows. Both waves compute h1 (identical
// bits). Wave w: h2j for j in [50w,50w+50), inner loop VERBATIM R0.
// Wave 0 after barrier: h3 chain in exact j order, layer 4, store.
// ---------------------------------------------------------------------------
__global__ __launch_bounds__(128, 2) void mlp_kernel(
    const float* __restrict__ x, const float* __restrict__ nd,
    const float* __restrict__ W1, const float* __restrict__ b1,
    const float* __restrict__ W2T, const float* __restrict__ b2,
    const float* __restrict__ W3, const float* __restrict__ b3,
    const float* __restrict__ W4, const float* __restrict__ b4,
    float* __restrict__ outv)
{
    __shared__ float sh2[100 * 64];     // [j][lane], 25.6 KB, conflict-free

    const int lane = threadIdx.x & 63;
    const int wv   = threadIdx.x >> 6;              // 0 or 1
    const int r    = blockIdx.x * 64 + lane;        // 2176*64 = 139264 exact
    const float2 xi = (r < NQ) ? ((const float2*)x)[r]
                               : ((const float2*)nd)[r - NQ];

    // ---- layer 1: h1[100] (constant indices; identical in both waves) ----
    float h1[100];
#pragma unroll
    for (int k = 0; k < 100; ++k)
        h1[k] = fmaxf(fmaf(xi.x, W1[k], fmaf(xi.y, W1[100 + k], b1[k])), 0.0f);

    // ---- phase 1: wave wv computes h2j for its 50-row j-slice ----
    {
        const float* w2 = W2T + (50 * wv) * 100;
        const int j0 = 50 * wv;
        for (int jl = 0; jl < 50; ++jl) {
            const int j = j0 + jl;
            float a0 = 0.0f, a1 = 0.0f;             // 2 chains, VERBATIM R0
#pragma unroll
            for (int k = 0; k < 100; k += 2) {
                a0 = fmaf(h1[k],     w2[k],     a0);    // w2[k]: s_load scalar
                a1 = fmaf(h1[k + 1], w2[k + 1], a1);
            }
            sh2[j * 64 + lane] = fmaxf(a0 + a1 + b2[j], 0.0f);
            w2 += 100;
        }
    }
    __syncthreads();

    // ---- phase 2 (wave 0 only): h3 chain in exact j order, then layer 4 ----
    if (wv == 0) {
        float h3[30];
#pragma unroll
        for (int jj = 0; jj < 30; ++jj) h3[jj] = b3[jj];

        const float* w3 = W3;
        for (int j = 0; j < 100; ++j) {
            const float h2j = sh2[j * 64 + lane];   // exact fp32 pass-through
#pragma unroll
            for (int jj = 0; jj < 30; ++jj)
                h3[jj] = fmaf(h2j, w3[jj], h3[jj]); // w3[jj]: s_load scalar
            w3 += 30;
        }

        float o0 = b4[0], o1 = b4[1];
#pragma unroll
        for (int k = 0; k < 30; ++k) {
            const float h = fmaxf(h3[k], 0.0f);
            o0 = fmaf(h, W4[2 * k],     o0);
            o1 = fmaf(h, W4[2 * k + 1], o1);
        }
        ((float2*)outv)[r] = make_float2(o0, o1);
    }
}

// ---------------------------------------------------------------------------
// Kernel 2: per-internal-node stop-branch class mixture (query-independent).
// Verbatim (passed every round).
// ---------------------------------------------------------------------------
__global__ __launch_bounds__(256) void prob2_kernel(
    const float2* __restrict__ emb, const float2* __restrict__ cls,
    float2* __restrict__ p2)
{
    const int i = blockIdx.x * 256 + threadIdx.x;   // 0..1023
    const float2 ei = emb[i];
    const int base = 8 * i + 1;

    float d2[8];
    float m2 = BIGD;
#pragma unroll
    for (int j = 0; j < 8; ++j) {
        const int c = base + j;
        const bool v = c < MN;
        const float2 ec = emb[v ? c : 0];
        const float dx = ei.x - ec.x + EPSD;
        const float dy = ei.y - ec.y + EPSD;
        d2[j] = v ? sqrtf(dx * dx + dy * dy) : BIGD;
        m2 = fminf(m2, d2[j]);
    }
    float s2 = 0.0f, mix0 = 0.0f, mix1 = 0.0f;
#pragma unroll
    for (int j = 0; j < 8; ++j) {
        const float w = expf(m2 - d2[j]);   // exactly 0 for pads
        s2 += w;
        const int c = base + j;
        if (c < MN) {
            const float2 cv = cls[c];
            mix0 = fmaf(w, cv.x, mix0);
            mix1 = fmaf(w, cv.y, mix1);
        }
    }
    mix0 /= s2;
    mix1 /= s2;
    p2[i] = make_float2(logf(fmaxf(mix0, 1e-30f)),
                        logf(fmaxf(mix1, 1e-30f)));
}

// ---------------------------------------------------------------------------
// Kernel 3: per-query traversal (R3/R12 shape: LDS-staged emb with
// bank-decorrelated layout + sp2). d0 carried across steps, verbatim.
// ---------------------------------------------------------------------------
#define SEMB_F (2 * MN + MN / 8)    // 17408 floats = 68 KB

__global__ __launch_bounds__(256) void traverse_kernel(
    const float* __restrict__ qx, const float2* __restrict__ emb,
    const float2* __restrict__ p2g, float* __restrict__ out)
{
    __shared__ float sembf[SEMB_F];  // 68 KB, padded layout
    __shared__ float2 sp2[NINT];     // 8 KB
    {
        for (int c = threadIdx.x; c < MN; c += 256) {   // coalesced 8B/lane
            const float2 e = emb[c];
            const int off = 2 * c + (c >> 3);
            sembf[off]     = e.x;
            sembf[off + 1] = e.y;
        }
        const float4* gp = (const float4*)p2g;
        float4* sp = (float4*)sp2;
#pragma unroll
        for (int t = 0; t < 2; ++t)
            sp[threadIdx.x + 256 * t] = gp[threadIdx.x + 256 * t];
    }
    __syncthreads();

    const int qi = blockIdx.x * 256 + threadIdx.x;  // grid = NQ/256
    const float2 qv = ((const float2*)qx)[qi];

    int cur = 0;
    float d0;
    {
        const float ex = sembf[0], ey = sembf[1];   // node 0 at offset 0
        const float dx = ex - qv.x + EPSD;
        const float dy = ey - qv.y + EPSD;
        d0 = sqrtf(dx * dx + dy * dy);
    }
    float prob = 0.0f, out0 = 0.0f, out1 = 0.0f;
    bool done = false;

    for (int t = 0; t < DEPTHT; ++t) {
        if (__all(done)) break;
        if (!done) {
            const int base = 8 * cur + 1;
            const int boff = 17 * cur + 2;          // float offset of child 0

            float dc[8];
#pragma unroll
            for (int j = 0; j < 8; ++j) {
                const int c = base + j;
                const bool v = c < MN;
                const int off = v ? (boff + 2 * j + (j == 7 ? 1 : 0)) : 0;
                const float ex = sembf[off];
                const float ey = sembf[off + 1];
                const float dx = ex - qv.x + EPSD;
                const float dy = ey - qv.y + EPSD;
                dc[j] = v ? sqrtf(dx * dx + dy * dy) : BIGD;
            }

            // argmax(log_softmax(-d)) == first argmin(d)
            float dmin = d0;
            int amax = 0;
#pragma unroll
            for (int j = 0; j < 8; ++j)
                if (dc[j] < dmin) { dmin = dc[j]; amax = j + 1; }

            float s = expf(dmin - d0);
#pragma unroll
            for (int j = 0; j < 8; ++j) s += expf(dmin - dc[j]);
            const float max_prob = -logf(s);
            // quirk: t==0 adds max_prob twice
            const float prob_new = prob + max_prob + ((t == 0) ? max_prob : 0.0f);

            if (amax == 0) {
                if (base < MN) {                  // internal node
                    const float2 pp = sp2[cur];
                    out0 = prob_new + pp.x;
                    out1 = prob_new + pp.y;
                } else {                          // leaf
                    out0 = prob_new;
                    out1 = prob_new;
                }
                done = true;
            } else {
                cur  = base + amax - 1;
                d0   = dmin;                      // child dist == next d0
                prob = prob_new;
            }
        }
    }

    ((float2*)out)[qi] = make_float2(out0, out1);
}

// ---------------------------------------------------------------------------
extern "C" void kernel_launch(void* const* d_in, const int* in_sizes, int n_in,
                              void* d_out, int out_size, void* d_ws, size_t ws_size,
                              hipStream_t stream)
{
    const float* x   = (const float*)d_in[0];
    const float* nd  = (const float*)d_in[1];
    const float* cls = (const float*)d_in[2];
    // d_in[3] (children) unused: complete 8-ary tree, child = 8i+1+j if <8192
    const float* W1 = (const float*)d_in[4];
    const float* b1 = (const float*)d_in[5];
    const float* W2 = (const float*)d_in[6];
    const float* b2 = (const float*)d_in[7];
    const float* W3 = (const float*)d_in[8];
    const float* b3 = (const float*)d_in[9];
    const float* W4 = (const float*)d_in[10];
    const float* b4 = (const float*)d_in[11];

    float* ws   = (float*)d_ws;
    float* qx   = ws;                        // [NQ][2]
    float* embf = ws + 2 * NQ;               // [MN][2]  (contiguous after qx)
    float* p2f  = ws + 2 * (NQ + MN);        // [NINT][2]
    float* w2t  = p2f + 2 * NINT;            // [100][100]

    transpose_w2<<<40, 256, 0, stream>>>(W2, w2t);

    // team-of-2: 2176 blocks x 128 threads, 64 rows/block
    mlp_kernel<<<(NQ + MN) / 64, 128, 0, stream>>>(
        x, nd, W1, b1, w2t, b2, W3, b3, W4, b4, qx);

    prob2_kernel<<<NINT / 256, 256, 0, stream>>>(
        (const float2*)embf, (const float2*)cls, (float2*)p2f);

    traverse_kernel<<<NQ / 256, 256, 0, stream>>>(
        qx, (const float2*)embf, (const float2*)p2f, (float*)d_out);
}